// Round 7
// baseline (278.457 us; speedup 1.0000x reference)
//
#include <hip/hip_runtime.h>
#include <hip/hip_bf16.h>
#include <stdint.h>

// Problem constants: B=2, S=T=2048, D=2048, N=8 heads, K=1 kv head, H=256
#define BB 2
#define SS 2048
#define DD 2048
#define NHEAD 8
#define HH 256

typedef __bf16 bf16_t;
typedef __bf16 bf16x8 __attribute__((ext_vector_type(8)));
typedef __bf16 bf16x4v __attribute__((ext_vector_type(4)));
typedef __bf16 bf16x2v __attribute__((ext_vector_type(2)));
typedef float f32x4 __attribute__((ext_vector_type(4)));
typedef float f32x16 __attribute__((ext_vector_type(16)));
typedef unsigned int u32;

__device__ static inline void gload_lds16(const void* g, void* l) {
  __builtin_amdgcn_global_load_lds(
      (__attribute__((address_space(1))) void*)(g),
      (__attribute__((address_space(3))) void*)(l), 16, 0, 0);
}

__device__ static inline u32 pk2(float a, float b) {
  bf16x2v t = {(bf16_t)a, (bf16_t)b};
  return __builtin_bit_cast(u32, t);
}

// ---------------- x -> bf16 ----------------
__global__ void cvt_x_kernel(const float* __restrict__ x, bf16_t* __restrict__ xb) {
  size_t i = ((size_t)blockIdx.x * 256 + threadIdx.x) * 4;
  float4 v = *(const float4*)(x + i);
  bf16x4v o = {(bf16_t)v.x, (bf16_t)v.y, (bf16_t)v.z, (bf16_t)v.w};
  *(bf16x4v*)(xb + i) = o;
}

// ---------------- tiled transpose+convert: out[c][r] = (bf16)in[r][c] ----------------
__global__ void transpose_cvt(const float* __restrict__ in, bf16_t* __restrict__ out,
                              int R, int C) {
  __shared__ float tile[32][33];
  int bx = blockIdx.x, by = blockIdx.y, z = blockIdx.z;
  in  += (size_t)z * R * C;
  out += (size_t)z * R * C;
  int tx = threadIdx.x & 31, ty = threadIdx.x >> 5;  // 32x8
#pragma unroll
  for (int k = 0; k < 4; ++k) {
    int r = by * 32 + ty + k * 8, c = bx * 32 + tx;
    tile[ty + k * 8][tx] = in[(size_t)r * C + c];
  }
  __syncthreads();
#pragma unroll
  for (int k = 0; k < 4; ++k) {
    int c = bx * 32 + ty + k * 8, r = by * 32 + tx;
    out[(size_t)c * R + r] = (bf16_t)tile[tx][ty + k * 8];
  }
}

// ---------------- GEMM: C[M][Nc] = A[M][Kd] * BT[Nc][Kd]^T  (bf16 in, fp32 acc) ----------------
template <int OUT_F32>
__global__ __launch_bounds__(256) void gemm_bt(const bf16_t* __restrict__ A,
                                               const bf16_t* __restrict__ BT,
                                               void* __restrict__ C,
                                               int M, int Nc, int Kd) {
  __shared__ bf16_t At[128 * 64];
  __shared__ bf16_t Bt[128 * 64];
  const int ntiles = Nc >> 7;
  int bid = blockIdx.x;
  int mt = bid / ntiles, ntb = bid % ntiles;
  int t = threadIdx.x;
  int lane = t & 63, w = t >> 6;
  int wm = w >> 1, wn = w & 1;
  int l15 = lane & 15, lg = lane >> 4;
  f32x4 acc[4][4] = {};
  for (int kt = 0; kt < Kd; kt += 64) {
#pragma unroll
    for (int r = 0; r < 4; ++r) {
      int o = t * 16 + r * 4096;     // byte offset into 16KB tile
      int row = o >> 7;              // 128B per row (64 bf16)
      int cb = o & 127;
      gload_lds16(A + (size_t)(mt * 128 + row) * Kd + kt + (cb >> 1), (char*)At + o);
      gload_lds16(BT + (size_t)(ntb * 128 + row) * Kd + kt + (cb >> 1), (char*)Bt + o);
    }
    __syncthreads();
#pragma unroll
    for (int ks = 0; ks < 2; ++ks) {
      bf16x8 af[4], bfr[4];
#pragma unroll
      for (int i = 0; i < 4; ++i) {
        af[i]  = *(const bf16x8*)(At + (wm * 64 + i * 16 + l15) * 64 + ks * 32 + lg * 8);
        bfr[i] = *(const bf16x8*)(Bt + (wn * 64 + i * 16 + l15) * 64 + ks * 32 + lg * 8);
      }
      __builtin_amdgcn_s_setprio(1);
#pragma unroll
      for (int i = 0; i < 4; ++i)
#pragma unroll
        for (int j = 0; j < 4; ++j)
          acc[i][j] = __builtin_amdgcn_mfma_f32_16x16x32_bf16(af[i], bfr[j], acc[i][j], 0, 0, 0);
      __builtin_amdgcn_s_setprio(0);
    }
    __syncthreads();
  }
#pragma unroll
  for (int i = 0; i < 4; ++i)
#pragma unroll
    for (int j = 0; j < 4; ++j) {
      int row = mt * 128 + wm * 64 + i * 16 + lg * 4;
      int col = ntb * 128 + wn * 64 + j * 16 + l15;
#pragma unroll
      for (int v = 0; v < 4; ++v) {
        if (OUT_F32)
          ((float*)C)[(size_t)(row + v) * Nc + col] = acc[i][j][v];
        else
          ((bf16_t*)C)[(size_t)(row + v) * Nc + col] = (bf16_t)acc[i][j][v];
      }
    }
}

// ---------------- RoPE (in-place) on fused qkv [4096][2560] ----------------
__global__ void rope_kernel(bf16_t* __restrict__ qkv, const int* __restrict__ positions) {
  int idx = blockIdx.x * 256 + threadIdx.x;
  const int QP = 4096 * 8 * 128;
  int i, row;
  bf16_t *p1, *p2;
  float scl;
  if (idx < QP) {
    i = idx & 127;
    int nh = (idx >> 7) & 7;
    row = idx >> 10;
    p1 = qkv + (size_t)row * 2560 + nh * 256 + i;
    p2 = p1 + 128;
    scl = 0.0625f;  // H^-0.5 = 1/16
  } else {
    int kk = idx - QP;
    if (kk >= 4096 * 128) return;
    i = kk & 127;
    row = kk >> 7;
    p1 = qkv + (size_t)row * 2560 + 2048 + i;
    p2 = p1 + 128;
    scl = 1.0f;
  }
  float pos = (float)positions[row];
  float ang = pos * __expf(-(float)i * (9.2103403719761836f / 128.f));
  float s = sinf(ang), c = cosf(ang);
  float x1 = (float)*p1, x2 = (float)*p2;
  *p1 = (bf16_t)((x1 * c - x2 * s) * scl);
  *p2 = (bf16_t)((x2 * c + x1 * s) * scl);
}

// ---------------- V transpose (LDS-tiled): vt[b][h][s] = qkv[(b*S+s)][2304+h] ----------------
__global__ void vt_kernel(const bf16_t* __restrict__ qkv, bf16_t* __restrict__ vt) {
  __shared__ bf16_t tile[32][34];
  int bx = blockIdx.x;  // s-tile (64)
  int by = blockIdx.y;  // h-tile (8)
  int b = blockIdx.z;
  int tx = threadIdx.x & 31, ty = threadIdx.x >> 5;
#pragma unroll
  for (int k = 0; k < 4; ++k) {
    int s = bx * 32 + ty + k * 8, h = by * 32 + tx;
    tile[ty + k * 8][tx] = qkv[((size_t)(b * SS + s)) * 2560 + 2304 + h];
  }
  __syncthreads();
#pragma unroll
  for (int k = 0; k < 4; ++k) {
    int h = by * 32 + ty + k * 8, s = bx * 32 + tx;
    vt[((size_t)(b * HH + h)) * 2048 + s] = tile[tx][ty + k * 8];
  }
}

// ---------------- Flash attention: 32x32 MFMA, in-register P, s-split 8 waves ----------------
// grid 256, block 512 = 8 waves. Wave w: q-rows (w&3)*32 of the 128-row q-tile,
// s-half (w>>2) of each 64-wide KV tile. q = lane&31 everywhere (swapped QK^T and
// q-on-rows PV) -> per-lane scalar softmax stats; P redistributed in-register.
// waves_per_eu(2,2): pin min=max=2 waves/EU -> 256-VGPR budget (r5/r6's min-only
// variants let the compiler target 4/EU and cap at 128 -> 40MB spill traffic).
// Q staged through the idle buf-1 LDS once per q-tile (coalesced) then ds_read.
__global__ __attribute__((amdgpu_flat_work_group_size(512, 512),
                          amdgpu_waves_per_eu(2, 2)))
void flash_kernel(const bf16_t* __restrict__ qkv, const bf16_t* __restrict__ vtg,
                  bf16_t* __restrict__ enc) {
  __shared__ __attribute__((aligned(16))) char LDSRAW[133120];
  // [0,64K): K dbuf [2][64][256]b, 512B rows, XOR-swizzle ^((row&15)<<4)
  // [64K,128K): V^T dbuf [2][256][64]b, 128B rows, XOR-swizzle ^((row&7)<<4)
  // [128K,130K): merge stats; Ox overlay @0 (after kt loop); Q staged in buf1 regions
  int bid = blockIdx.x;
  int b = bid >> 7, n = (bid >> 4) & 7, pr = bid & 15;
  int t = threadIdx.x, lane = t & 63, w = t >> 6;
  int l31 = lane & 31, h5 = lane >> 5;
  int wq = w & 3, sh = w >> 2;
  char* Kt0 = LDSRAW;
  char* Vt0 = LDSRAW + 65536;
  float* stw = (float*)(LDSRAW + 131072);
  // staging source pointers (pre-swizzled global addr, LDS dest linear)
  int rk0 = t >> 5;  // K rows: rk0 + 16*r  (row&15 invariant)
  int cbk = ((t * 16) & 511) ^ ((rk0 & 15) << 4);
  const bf16_t* kptr = qkv + ((size_t)(b * SS + rk0)) * 2560 + 2048 + (cbk >> 1);
  int rv0 = t >> 3;  // V rows: rv0 + 64*r  (row&7 invariant)
  int cbv = ((t & 7) * 16) ^ ((rv0 & 7) << 4);
  const bf16_t* vptr = vtg + ((size_t)(b * HH + rv0)) * 2048 + (cbv >> 1);
  // Q staging: same row/swizzle pattern as K (512B rows, ^((row&15)<<4))
  int rq0 = t >> 5;  // Q rows rq0 + 16*r, r=0..7 (128 rows)
  int cbq = ((t * 16) & 511) ^ ((rq0 & 15) << 4);

  for (int half = 0; half < 2; ++half) {
    int qtile = half ? (15 - pr) : pr;
    int qmin = qtile * 128 + wq * 32;
    int ktlast = 2 * qtile + 1;
    int q_g = qmin + l31;  // this lane's q row (global)
    // ---- stage Q[128][256] into buf-1 regions: rows 0-63 -> Kt[1], 64-127 -> Vt[1]
    {
      const bf16_t* qsrc =
          qkv + ((size_t)(b * SS + qtile * 128 + rq0)) * 2560 + n * 256 + (cbq >> 1);
#pragma unroll
      for (int r = 0; r < 8; ++r) {
        int off = t * 16 + r * 8192;  // [0,64K); r<4 -> Kt[1], r>=4 -> Vt[1]
        char* dst = (r < 4) ? (Kt0 + 32768 + off) : (Vt0 + off);
        gload_lds16(qsrc + (size_t)r * 16 * 2560, dst);
      }
    }
    __syncthreads();  // Q staged
    // issue kv-tile-0 staging into buf 0 (drained by the next barrier)
#pragma unroll
    for (int r = 0; r < 4; ++r) {
      gload_lds16(kptr + (size_t)r * 16 * 2560, Kt0 + t * 16 + r * 8192);
      gload_lds16(vptr + (size_t)r * 64 * 2048, Vt0 + t * 16 + r * 8192);
    }
    // read Q fragments from LDS (coalesced-staged): col q = l31, k-chunk hh
    bf16x8 qf[16];
    {
      int qrow_l = wq * 32 + l31;  // 0..127
      const char* Qb = (wq < 2) ? (Kt0 + 32768) : Vt0;  // row*512 maps into region
      int qswz = (qrow_l & 15) << 4;
#pragma unroll
      for (int hh = 0; hh < 16; ++hh)
        qf[hh] = *(const bf16x8*)(Qb + qrow_l * 512 + ((hh * 32 + h5 * 16) ^ qswz));
    }
    f32x16 accO[8] = {};
    float m_r = -1e30f, l_r = 0.f;
    __syncthreads();  // kv tile 0 staged (vmcnt(0) drain); Q reads complete
    int cur = 0;
    for (int kt = 0; kt <= ktlast; ++kt) {
      // issue next tile's staging FIRST (hidden under compute below)
      if (kt < ktlast) {
        int nxt = cur ^ 1;
        const bf16_t* ks = kptr + (size_t)(kt + 1) * 64 * 2560;
        const bf16_t* vs = vptr + (size_t)(kt + 1) * 64;
#pragma unroll
        for (int r = 0; r < 4; ++r) {
          gload_lds16(ks + (size_t)r * 16 * 2560, Kt0 + nxt * 32768 + t * 16 + r * 8192);
          gload_lds16(vs + (size_t)r * 64 * 2048, Vt0 + nxt * 32768 + t * 16 + r * 8192);
        }
      }
      int smin = kt * 64 + sh * 32;
      if (smin <= qmin + 31) {  // wave active for this sub-tile
        const char* Kc = Kt0 + cur * 32768;
        const char* Vc = Vt0 + cur * 32768;
        // QK^T swapped: S^T[32 s][32 q] = K x Q; s on C-rows, q = l31
        f32x16 sc = {};
        int krow = sh * 32 + l31;
        int kswz = (krow & 15) << 4;
        __builtin_amdgcn_s_setprio(1);
#pragma unroll
        for (int hh = 0; hh < 16; ++hh) {
          bf16x8 kf = *(const bf16x8*)(Kc + krow * 512 + ((hh * 32 + h5 * 16) ^ kswz));
          sc = __builtin_amdgcn_mfma_f32_32x32x16_bf16(kf, qf[hh], sc, 0, 0, 0);
        }
        __builtin_amdgcn_s_setprio(0);
        if (smin + 31 > qmin) {  // diagonal-crossing: causal mask
#pragma unroll
          for (int r = 0; r < 16; ++r) {
            int s_g = smin + ((r & 3) + 8 * (r >> 2) + 4 * h5);
            if (s_g > q_g) sc[r] = -1e30f;
          }
        }
        // per-lane softmax (lane = q): in-lane max over 16 + 1 shfl
        float pm = sc[0];
#pragma unroll
        for (int r = 1; r < 16; ++r) pm = fmaxf(pm, sc[r]);
        pm = fmaxf(pm, __shfl_xor(pm, 32));
        if (__any(pm > m_r + 8.f)) {  // defer-max rescale (rare)
          float mnew = fmaxf(m_r, pm);
          float rsc = __expf(m_r - mnew);
          m_r = mnew;
          l_r *= rsc;
          float rv[16];
#pragma unroll
          for (int r = 0; r < 16; ++r) rv[r] = __shfl(rsc, (r & 3) + 8 * (r >> 2) + 4 * h5);
#pragma unroll
          for (int ht = 0; ht < 8; ++ht)
#pragma unroll
            for (int r = 0; r < 16; ++r) accO[ht][r] *= rv[r];
        }
        float rs = 0.f;
#pragma unroll
        for (int r = 0; r < 16; ++r) {
          float p = __expf(sc[r] - m_r);
          sc[r] = p;
          rs += p;
        }
        rs += __shfl_xor(rs, 32);
        l_r += rs;
        // build PV A-fragments in-register: lane needs P[s=ks*16+h5*8+j][q=l31]
        u32 u0 = pk2(sc[0], sc[1]),  u1 = pk2(sc[2], sc[3]);
        u32 u2 = pk2(sc[4], sc[5]),  u3 = pk2(sc[6], sc[7]);
        u32 u4 = pk2(sc[8], sc[9]),  u5 = pk2(sc[10], sc[11]);
        u32 u6 = pk2(sc[12], sc[13]), u7 = pk2(sc[14], sc[15]);
        u32 x0 = __shfl_xor(u0, 32), x1 = __shfl_xor(u1, 32);
        u32 x2 = __shfl_xor(u2, 32), x3 = __shfl_xor(u3, 32);
        u32 x4 = __shfl_xor(u4, 32), x5 = __shfl_xor(u5, 32);
        u32 x6 = __shfl_xor(u6, 32), x7 = __shfl_xor(u7, 32);
        union { u32 wd[4]; bf16x8 v; } f0, f1;
        f0.wd[0] = h5 ? x2 : u0;  f0.wd[1] = h5 ? x3 : u1;
        f0.wd[2] = h5 ? u2 : x0;  f0.wd[3] = h5 ? u3 : x1;
        f1.wd[0] = h5 ? x6 : u4;  f1.wd[1] = h5 ? x7 : u5;
        f1.wd[2] = h5 ? u6 : x4;  f1.wd[3] = h5 ? u7 : x5;
        // PV: O[32 q][256 h] += P[32 q][32 s] * V[32 s][256 h]; q on C-rows
        __builtin_amdgcn_s_setprio(1);
#pragma unroll
        for (int ht = 0; ht < 8; ++ht) {
          int vrow = ht * 32 + l31;
          int vswz = (vrow & 7) << 4;
          bf16x8 vf0 = *(const bf16x8*)(Vc + vrow * 128 + ((sh * 64 + h5 * 16) ^ vswz));
          bf16x8 vf1 = *(const bf16x8*)(Vc + vrow * 128 + ((sh * 64 + 32 + h5 * 16) ^ vswz));
          accO[ht] = __builtin_amdgcn_mfma_f32_32x32x16_bf16(f0.v, vf0, accO[ht], 0, 0, 0);
          accO[ht] = __builtin_amdgcn_mfma_f32_32x32x16_bf16(f1.v, vf1, accO[ht], 0, 0, 0);
        }
        __builtin_amdgcn_s_setprio(0);
      }
      __syncthreads();  // implicit vmcnt(0): next tile staged; buf[cur] reusable
      cur ^= 1;
    }
    // ---- merge wave pairs (w, w^4): disjoint s-sets, same q rows ----
    if (h5 == 0) {
      stw[(w * 32 + l31) * 2 + 0] = m_r;
      stw[(w * 32 + l31) * 2 + 1] = l_r;
    }
    __syncthreads();
    int peer = w ^ 4;
    float pm2 = stw[(peer * 32 + l31) * 2 + 0];
    float pl2 = stw[(peer * 32 + l31) * 2 + 1];
    float* Ox = (float*)LDSRAW + (size_t)wq * 8192;  // [32 q][256 h] f32
    if (sh == 1) {  // upper half: write O2 * exp(m2 - m*)
      float sc2 = __expf(m_r - fmaxf(m_r, pm2));
      float s2v[16];
#pragma unroll
      for (int r = 0; r < 16; ++r) s2v[r] = __shfl(sc2, (r & 3) + 8 * (r >> 2) + 4 * h5);
#pragma unroll
      for (int ht = 0; ht < 8; ++ht)
#pragma unroll
        for (int r = 0; r < 16; ++r) {
          int ql = (r & 3) + 8 * (r >> 2) + 4 * h5;
          Ox[ql * 256 + ht * 32 + l31] = accO[ht][r] * s2v[r];
        }
    }
    __syncthreads();
    if (sh == 0) {  // lower half: combine, normalize, store
      float mstar = fmaxf(m_r, pm2);
      float sc1 = __expf(m_r - mstar);
      float lstar = l_r * sc1 + pl2 * __expf(pm2 - mstar);
      float rinv = 1.f / lstar;
      float s1v[16], riv[16];
#pragma unroll
      for (int r = 0; r < 16; ++r) {
        int ql = (r & 3) + 8 * (r >> 2) + 4 * h5;
        s1v[r] = __shfl(sc1, ql);
        riv[r] = __shfl(rinv, ql);
      }
#pragma unroll
      for (int ht = 0; ht < 8; ++ht)
#pragma unroll
        for (int r = 0; r < 16; ++r) {
          int ql = (r & 3) + 8 * (r >> 2) + 4 * h5;
          float o = (accO[ht][r] * s1v[r] + Ox[ql * 256 + ht * 32 + l31]) * riv[r];
          enc[((size_t)(b * SS + qmin + ql)) * 2048 + n * 256 + ht * 32 + l31] = (bf16_t)o;
        }
    }
    __syncthreads();  // Ox region reused as K/V/Q staging next half
  }
}

extern "C" void kernel_launch(void* const* d_in, const int* in_sizes, int n_in,
                              void* d_out, int out_size, void* d_ws, size_t ws_size,
                              hipStream_t stream) {
  const float* x = (const float*)d_in[0];
  const int* positions = (const int*)d_in[1];
  // d_in[2] = attn_mask (causal tril) — implemented analytically
  const float* qw = (const float*)d_in[3];
  const float* kvw = (const float*)d_in[4];
  const float* outw = (const float*)d_in[5];

  char* ws = (char*)d_ws;
  if (ws_size < (size_t)75497472) return;  // need ~72MB scratch
  bf16_t* xb      = (bf16_t*)(ws);             // [4096][2048]
  bf16_t* qkvwbt  = (bf16_t*)(ws + 16777216);  // [2560][2048]: q rows 0..2047, k 2048..2303, v 2304..2559
  bf16_t* outwbt  = (bf16_t*)(ws + 27262976);  // [2048][2048]
  bf16_t* qkvb    = (bf16_t*)(ws + 35651584);  // [4096][2560]
  bf16_t* vtg     = (bf16_t*)(ws + 56623104);  // [2][256][2048]
  bf16_t* encb    = (bf16_t*)(ws + 58720256);  // [4096][2048]

  cvt_x_kernel<<<8192, 256, 0, stream>>>(x, xb);
  transpose_cvt<<<dim3(8, 64, 8), 256, 0, stream>>>(qw, qkvwbt, 2048, 256);
  transpose_cvt<<<dim3(8, 64, 2), 256, 0, stream>>>(kvw, qkvwbt + (size_t)2048 * 2048, 2048, 256);
  transpose_cvt<<<dim3(64, 64, 1), 256, 0, stream>>>(outw, outwbt, 2048, 2048);
  gemm_bt<0><<<640, 256, 0, stream>>>(xb, qkvwbt, qkvb, 4096, 2560, 2048);
  rope_kernel<<<18432, 256, 0, stream>>>(qkvb, positions);
  vt_kernel<<<dim3(64, 8, 2), 256, 0, stream>>>(qkvb, vtg);
  flash_kernel<<<256, 512, 0, stream>>>(qkvb, vtg, encb);
  gemm_bt<1><<<512, 256, 0, stream>>>(encb, outwbt, d_out, 4096, 2048, 2048);
}

// Round 8
// 234.235 us; speedup vs baseline: 1.1888x; 1.1888x over previous
//
#include <hip/hip_runtime.h>
#include <hip/hip_bf16.h>
#include <stdint.h>

// Problem constants: B=2, S=T=2048, D=2048, N=8 heads, K=1 kv head, H=256
#define BB 2
#define SS 2048
#define DD 2048
#define NHEAD 8
#define HH 256

typedef __bf16 bf16_t;
typedef __bf16 bf16x8 __attribute__((ext_vector_type(8)));
typedef __bf16 bf16x4v __attribute__((ext_vector_type(4)));
typedef __bf16 bf16x2v __attribute__((ext_vector_type(2)));
typedef float f32x4 __attribute__((ext_vector_type(4)));
typedef float f32x16 __attribute__((ext_vector_type(16)));
typedef unsigned int u32;

__device__ static inline void gload_lds16(const void* g, void* l) {
  __builtin_amdgcn_global_load_lds(
      (__attribute__((address_space(1))) void*)(g),
      (__attribute__((address_space(3))) void*)(l), 16, 0, 0);
}

__device__ static inline u32 pk2(float a, float b) {
  bf16x2v t = {(bf16_t)a, (bf16_t)b};
  return __builtin_bit_cast(u32, t);
}

// ---------------- x -> bf16 ----------------
__global__ void cvt_x_kernel(const float* __restrict__ x, bf16_t* __restrict__ xb) {
  size_t i = ((size_t)blockIdx.x * 256 + threadIdx.x) * 4;
  float4 v = *(const float4*)(x + i);
  bf16x4v o = {(bf16_t)v.x, (bf16_t)v.y, (bf16_t)v.z, (bf16_t)v.w};
  *(bf16x4v*)(xb + i) = o;
}

// ---------------- tiled transpose+convert: out[c][r] = (bf16)in[r][c] ----------------
__global__ void transpose_cvt(const float* __restrict__ in, bf16_t* __restrict__ out,
                              int R, int C) {
  __shared__ float tile[32][33];
  int bx = blockIdx.x, by = blockIdx.y, z = blockIdx.z;
  in  += (size_t)z * R * C;
  out += (size_t)z * R * C;
  int tx = threadIdx.x & 31, ty = threadIdx.x >> 5;  // 32x8
#pragma unroll
  for (int k = 0; k < 4; ++k) {
    int r = by * 32 + ty + k * 8, c = bx * 32 + tx;
    tile[ty + k * 8][tx] = in[(size_t)r * C + c];
  }
  __syncthreads();
#pragma unroll
  for (int k = 0; k < 4; ++k) {
    int c = bx * 32 + ty + k * 8, r = by * 32 + tx;
    out[(size_t)c * R + r] = (bf16_t)tile[tx][ty + k * 8];
  }
}

// ---------------- GEMM: C[M][Nc] = A[M][Kd] * BT[Nc][Kd]^T  (bf16 in, fp32 acc) ----------------
template <int OUT_F32>
__global__ __launch_bounds__(256) void gemm_bt(const bf16_t* __restrict__ A,
                                               const bf16_t* __restrict__ BT,
                                               void* __restrict__ C,
                                               int M, int Nc, int Kd) {
  __shared__ bf16_t At[128 * 64];
  __shared__ bf16_t Bt[128 * 64];
  const int ntiles = Nc >> 7;
  int bid = blockIdx.x;
  int mt = bid / ntiles, ntb = bid % ntiles;
  int t = threadIdx.x;
  int lane = t & 63, w = t >> 6;
  int wm = w >> 1, wn = w & 1;
  int l15 = lane & 15, lg = lane >> 4;
  f32x4 acc[4][4] = {};
  for (int kt = 0; kt < Kd; kt += 64) {
#pragma unroll
    for (int r = 0; r < 4; ++r) {
      int o = t * 16 + r * 4096;     // byte offset into 16KB tile
      int row = o >> 7;              // 128B per row (64 bf16)
      int cb = o & 127;
      gload_lds16(A + (size_t)(mt * 128 + row) * Kd + kt + (cb >> 1), (char*)At + o);
      gload_lds16(BT + (size_t)(ntb * 128 + row) * Kd + kt + (cb >> 1), (char*)Bt + o);
    }
    __syncthreads();
#pragma unroll
    for (int ks = 0; ks < 2; ++ks) {
      bf16x8 af[4], bfr[4];
#pragma unroll
      for (int i = 0; i < 4; ++i) {
        af[i]  = *(const bf16x8*)(At + (wm * 64 + i * 16 + l15) * 64 + ks * 32 + lg * 8);
        bfr[i] = *(const bf16x8*)(Bt + (wn * 64 + i * 16 + l15) * 64 + ks * 32 + lg * 8);
      }
      __builtin_amdgcn_s_setprio(1);
#pragma unroll
      for (int i = 0; i < 4; ++i)
#pragma unroll
        for (int j = 0; j < 4; ++j)
          acc[i][j] = __builtin_amdgcn_mfma_f32_16x16x32_bf16(af[i], bfr[j], acc[i][j], 0, 0, 0);
      __builtin_amdgcn_s_setprio(0);
    }
    __syncthreads();
  }
#pragma unroll
  for (int i = 0; i < 4; ++i)
#pragma unroll
    for (int j = 0; j < 4; ++j) {
      int row = mt * 128 + wm * 64 + i * 16 + lg * 4;
      int col = ntb * 128 + wn * 64 + j * 16 + l15;
#pragma unroll
      for (int v = 0; v < 4; ++v) {
        if (OUT_F32)
          ((float*)C)[(size_t)(row + v) * Nc + col] = acc[i][j][v];
        else
          ((bf16_t*)C)[(size_t)(row + v) * Nc + col] = (bf16_t)acc[i][j][v];
      }
    }
}

// ---------------- RoPE (in-place) on fused qkv [4096][2560] ----------------
__global__ void rope_kernel(bf16_t* __restrict__ qkv, const int* __restrict__ positions) {
  int idx = blockIdx.x * 256 + threadIdx.x;
  const int QP = 4096 * 8 * 128;
  int i, row;
  bf16_t *p1, *p2;
  float scl;
  if (idx < QP) {
    i = idx & 127;
    int nh = (idx >> 7) & 7;
    row = idx >> 10;
    p1 = qkv + (size_t)row * 2560 + nh * 256 + i;
    p2 = p1 + 128;
    scl = 0.0625f;  // H^-0.5 = 1/16
  } else {
    int kk = idx - QP;
    if (kk >= 4096 * 128) return;
    i = kk & 127;
    row = kk >> 7;
    p1 = qkv + (size_t)row * 2560 + 2048 + i;
    p2 = p1 + 128;
    scl = 1.0f;
  }
  float pos = (float)positions[row];
  float ang = pos * __expf(-(float)i * (9.2103403719761836f / 128.f));
  float s = sinf(ang), c = cosf(ang);
  float x1 = (float)*p1, x2 = (float)*p2;
  *p1 = (bf16_t)((x1 * c - x2 * s) * scl);
  *p2 = (bf16_t)((x2 * c + x1 * s) * scl);
}

// ---------------- V transpose (LDS-tiled): vt[b][h][s] = qkv[(b*S+s)][2304+h] ----------------
__global__ void vt_kernel(const bf16_t* __restrict__ qkv, bf16_t* __restrict__ vt) {
  __shared__ bf16_t tile[32][34];
  int bx = blockIdx.x;  // s-tile (64)
  int by = blockIdx.y;  // h-tile (8)
  int b = blockIdx.z;
  int tx = threadIdx.x & 31, ty = threadIdx.x >> 5;
#pragma unroll
  for (int k = 0; k < 4; ++k) {
    int s = bx * 32 + ty + k * 8, h = by * 32 + tx;
    tile[ty + k * 8][tx] = qkv[((size_t)(b * SS + s)) * 2560 + 2304 + h];
  }
  __syncthreads();
#pragma unroll
  for (int k = 0; k < 4; ++k) {
    int h = by * 32 + ty + k * 8, s = bx * 32 + tx;
    vt[((size_t)(b * HH + h)) * 2048 + s] = tile[tx][ty + k * 8];
  }
}

// ---------------- Flash attention: 32x32 MFMA, in-reg P, 4 waves (256 thr) ----------------
// grid 256, block 256 = 4 waves. QBLK=64: wave w handles q-rows (w&1)*32, s-half
// (w>>1) of each 64-wide KV tile. q = lane&31 everywhere -> per-lane scalar
// softmax stats; P redistributed in-register (pack + shfl_xor(32) + select).
// Pair merge (w^2) via LDS at q-tile end. Block does q-tiles pr and 31-pr
// (33 iters, balanced). 1 wave/SIMD -> 512-reg budget -> NO SPILL (the r5-r7
// 512-thread variants pinned 128 arch VGPRs and spilled ~50MB/dispatch).
__global__ __launch_bounds__(256, 1)
void flash_kernel(const bf16_t* __restrict__ qkv, const bf16_t* __restrict__ vtg,
                  bf16_t* __restrict__ enc) {
  __shared__ __attribute__((aligned(16))) char LDSRAW[133120];
  // [0,64K): K dbuf [2][64][256]b, 512B rows, XOR-swizzle ^((row&15)<<4)
  // [64K,128K): V^T dbuf [2][256][64]b, 128B rows, XOR-swizzle ^((row&7)<<4)
  // [128K,130K): merge stats; Ox overlay @0 [2 wq][32 q][256 h] f32 (after kt loop)
  int bid = blockIdx.x;
  int b = bid >> 7, n = (bid >> 4) & 7, pr = bid & 15;
  int t = threadIdx.x, lane = t & 63, w = t >> 6;
  int l31 = lane & 31, h5 = lane >> 5;
  int wq = w & 1, sh = w >> 1;
  char* Kt0 = LDSRAW;
  char* Vt0 = LDSRAW + 65536;
  float* stw = (float*)(LDSRAW + 131072);
  // staging patterns (256 thr, 8 chunks each for K and V; pre-swizzled global src)
  int rk0 = t >> 5;               // K row base (0..7), rows rk0+8r
  int kcol = (t * 16) & 511;      // byte col in 512B K row
  int rv0 = t >> 3;               // V^T row base (0..31), rows rv0+32r
  int cbv = ((t & 7) * 16) ^ ((rv0 & 7) << 4);  // row&7 invariant under +32
  const bf16_t* kbase = qkv + (size_t)(b * SS) * 2560 + 2048;
  const bf16_t* vbase = vtg + ((size_t)(b * HH + rv0)) * 2048 + (cbv >> 1);

  for (int half = 0; half < 2; ++half) {
    int qtile = half ? (31 - pr) : pr;
    int qmin = qtile * 64 + wq * 32;
    int ktlast = qtile;
    int q_g = qmin + l31;  // this lane's q row (global)
    // Q fragments direct from global (L2-resident): col q = l31, k-chunk hh
    bf16x8 qf[16];
    const bf16_t* qrow = qkv + ((size_t)(b * SS + q_g)) * 2560 + n * 256 + h5 * 8;
#pragma unroll
    for (int hh = 0; hh < 16; ++hh) qf[hh] = *(const bf16x8*)(qrow + hh * 16);
    f32x16 accO[8] = {};
    float m_r = -1e30f, l_r = 0.f;
    // prologue: stage kv tile 0 into buf 0
#pragma unroll
    for (int r = 0; r < 8; ++r) {
      int krow = rk0 + 8 * r;
      int cbk = kcol ^ ((krow & 15) << 4);
      gload_lds16(kbase + (size_t)krow * 2560 + (cbk >> 1), Kt0 + t * 16 + r * 4096);
      gload_lds16(vbase + (size_t)r * 32 * 2048, Vt0 + t * 16 + r * 4096);
    }
    __syncthreads();
    int cur = 0;
    for (int kt = 0; kt <= ktlast; ++kt) {
      // issue next tile's staging FIRST (hidden under compute below)
      if (kt < ktlast) {
        int nxt = cur ^ 1;
        const bf16_t* ks = kbase + (size_t)(kt + 1) * 64 * 2560;
        const bf16_t* vs = vbase + (size_t)(kt + 1) * 64;
#pragma unroll
        for (int r = 0; r < 8; ++r) {
          int krow = rk0 + 8 * r;
          int cbk = kcol ^ ((krow & 15) << 4);
          gload_lds16(ks + (size_t)krow * 2560 + (cbk >> 1),
                      Kt0 + nxt * 32768 + t * 16 + r * 4096);
          gload_lds16(vs + (size_t)r * 32 * 2048, Vt0 + nxt * 32768 + t * 16 + r * 4096);
        }
      }
      int smin = kt * 64 + sh * 32;
      if (smin <= qmin + 31) {  // wave active for this sub-tile
        const char* Kc = Kt0 + cur * 32768;
        const char* Vc = Vt0 + cur * 32768;
        // QK^T swapped: S^T[32 s][32 q] = K x Q; s on C-rows, q = l31
        f32x16 sc = {};
        int krow = sh * 32 + l31;
        int kswz = (krow & 15) << 4;
        __builtin_amdgcn_s_setprio(1);
#pragma unroll
        for (int hh = 0; hh < 16; ++hh) {
          bf16x8 kf = *(const bf16x8*)(Kc + krow * 512 + ((hh * 32 + h5 * 16) ^ kswz));
          sc = __builtin_amdgcn_mfma_f32_32x32x16_bf16(kf, qf[hh], sc, 0, 0, 0);
        }
        __builtin_amdgcn_s_setprio(0);
        if (smin + 31 > qmin) {  // diagonal-crossing: causal mask
#pragma unroll
          for (int r = 0; r < 16; ++r) {
            int s_g = smin + ((r & 3) + 8 * (r >> 2) + 4 * h5);
            if (s_g > q_g) sc[r] = -1e30f;
          }
        }
        // per-lane softmax (lane = q): in-lane max over 16 + 1 shfl
        float pm = sc[0];
#pragma unroll
        for (int r = 1; r < 16; ++r) pm = fmaxf(pm, sc[r]);
        pm = fmaxf(pm, __shfl_xor(pm, 32));
        if (__any(pm > m_r + 8.f)) {  // defer-max rescale (rare)
          float mnew = fmaxf(m_r, pm);
          float rsc = __expf(m_r - mnew);
          m_r = mnew;
          l_r *= rsc;
          float rv[16];
#pragma unroll
          for (int r = 0; r < 16; ++r) rv[r] = __shfl(rsc, (r & 3) + 8 * (r >> 2) + 4 * h5);
#pragma unroll
          for (int ht = 0; ht < 8; ++ht)
#pragma unroll
            for (int r = 0; r < 16; ++r) accO[ht][r] *= rv[r];
        }
        float rs = 0.f;
#pragma unroll
        for (int r = 0; r < 16; ++r) {
          float p = __expf(sc[r] - m_r);
          sc[r] = p;
          rs += p;
        }
        rs += __shfl_xor(rs, 32);
        l_r += rs;
        // build PV A-fragments in-register: lane needs P[s=ks*16+h5*8+j][q=l31]
        u32 u0 = pk2(sc[0], sc[1]),  u1 = pk2(sc[2], sc[3]);
        u32 u2 = pk2(sc[4], sc[5]),  u3 = pk2(sc[6], sc[7]);
        u32 u4 = pk2(sc[8], sc[9]),  u5 = pk2(sc[10], sc[11]);
        u32 u6 = pk2(sc[12], sc[13]), u7 = pk2(sc[14], sc[15]);
        u32 x0 = __shfl_xor(u0, 32), x1 = __shfl_xor(u1, 32);
        u32 x2 = __shfl_xor(u2, 32), x3 = __shfl_xor(u3, 32);
        u32 x4 = __shfl_xor(u4, 32), x5 = __shfl_xor(u5, 32);
        u32 x6 = __shfl_xor(u6, 32), x7 = __shfl_xor(u7, 32);
        union { u32 wd[4]; bf16x8 v; } f0, f1;
        f0.wd[0] = h5 ? x2 : u0;  f0.wd[1] = h5 ? x3 : u1;
        f0.wd[2] = h5 ? u2 : x0;  f0.wd[3] = h5 ? u3 : x1;
        f1.wd[0] = h5 ? x6 : u4;  f1.wd[1] = h5 ? x7 : u5;
        f1.wd[2] = h5 ? u6 : x4;  f1.wd[3] = h5 ? u7 : x5;
        // PV: O[32 q][256 h] += P[32 q][32 s] * V[32 s][256 h]; q on C-rows
        __builtin_amdgcn_s_setprio(1);
#pragma unroll
        for (int ht = 0; ht < 8; ++ht) {
          int vrow = ht * 32 + l31;
          int vswz = (vrow & 7) << 4;
          bf16x8 vf0 = *(const bf16x8*)(Vc + vrow * 128 + ((sh * 64 + h5 * 16) ^ vswz));
          bf16x8 vf1 = *(const bf16x8*)(Vc + vrow * 128 + ((sh * 64 + 32 + h5 * 16) ^ vswz));
          accO[ht] = __builtin_amdgcn_mfma_f32_32x32x16_bf16(f0.v, vf0, accO[ht], 0, 0, 0);
          accO[ht] = __builtin_amdgcn_mfma_f32_32x32x16_bf16(f1.v, vf1, accO[ht], 0, 0, 0);
        }
        __builtin_amdgcn_s_setprio(0);
      }
      __syncthreads();  // implicit vmcnt(0): next tile staged; buf[cur] reusable
      cur ^= 1;
    }
    // ---- merge wave pairs (w, w^2): disjoint s-halves, same q rows ----
    if (h5 == 0) {
      stw[(w * 32 + l31) * 2 + 0] = m_r;
      stw[(w * 32 + l31) * 2 + 1] = l_r;
    }
    __syncthreads();
    int peer = w ^ 2;
    float pm2 = stw[(peer * 32 + l31) * 2 + 0];
    float pl2 = stw[(peer * 32 + l31) * 2 + 1];
    float* Ox = (float*)LDSRAW + (size_t)wq * 8192;  // [32 q][256 h] f32
    if (sh == 1) {  // upper half: write O2 * exp(m2 - m*)
      float sc2 = __expf(m_r - fmaxf(m_r, pm2));
      float s2v[16];
#pragma unroll
      for (int r = 0; r < 16; ++r) s2v[r] = __shfl(sc2, (r & 3) + 8 * (r >> 2) + 4 * h5);
#pragma unroll
      for (int ht = 0; ht < 8; ++ht)
#pragma unroll
        for (int r = 0; r < 16; ++r) {
          int ql = (r & 3) + 8 * (r >> 2) + 4 * h5;
          Ox[ql * 256 + ht * 32 + l31] = accO[ht][r] * s2v[r];
        }
    }
    __syncthreads();
    if (sh == 0) {  // lower half: combine, normalize, store
      float mstar = fmaxf(m_r, pm2);
      float sc1 = __expf(m_r - mstar);
      float lstar = l_r * sc1 + pl2 * __expf(pm2 - mstar);
      float rinv = 1.f / lstar;
      float s1v[16], riv[16];
#pragma unroll
      for (int r = 0; r < 16; ++r) {
        int ql = (r & 3) + 8 * (r >> 2) + 4 * h5;
        s1v[r] = __shfl(sc1, ql);
        riv[r] = __shfl(rinv, ql);
      }
#pragma unroll
      for (int ht = 0; ht < 8; ++ht)
#pragma unroll
        for (int r = 0; r < 16; ++r) {
          int ql = (r & 3) + 8 * (r >> 2) + 4 * h5;
          float o = (accO[ht][r] * s1v[r] + Ox[ql * 256 + ht * 32 + l31]) * riv[r];
          enc[((size_t)(b * SS + qmin + ql)) * 2048 + n * 256 + ht * 32 + l31] = (bf16_t)o;
        }
    }
    __syncthreads();  // Ox region reused as K/V staging next half
  }
}

extern "C" void kernel_launch(void* const* d_in, const int* in_sizes, int n_in,
                              void* d_out, int out_size, void* d_ws, size_t ws_size,
                              hipStream_t stream) {
  const float* x = (const float*)d_in[0];
  const int* positions = (const int*)d_in[1];
  // d_in[2] = attn_mask (causal tril) — implemented analytically
  const float* qw = (const float*)d_in[3];
  const float* kvw = (const float*)d_in[4];
  const float* outw = (const float*)d_in[5];

  char* ws = (char*)d_ws;
  if (ws_size < (size_t)75497472) return;  // need ~72MB scratch
  bf16_t* xb      = (bf16_t*)(ws);             // [4096][2048]
  bf16_t* qkvwbt  = (bf16_t*)(ws + 16777216);  // [2560][2048]: q rows 0..2047, k 2048..2303, v 2304..2559
  bf16_t* outwbt  = (bf16_t*)(ws + 27262976);  // [2048][2048]
  bf16_t* qkvb    = (bf16_t*)(ws + 35651584);  // [4096][2560]
  bf16_t* vtg     = (bf16_t*)(ws + 56623104);  // [2][256][2048]
  bf16_t* encb    = (bf16_t*)(ws + 58720256);  // [4096][2048]

  cvt_x_kernel<<<8192, 256, 0, stream>>>(x, xb);
  transpose_cvt<<<dim3(8, 64, 8), 256, 0, stream>>>(qw, qkvwbt, 2048, 256);
  transpose_cvt<<<dim3(8, 64, 2), 256, 0, stream>>>(kvw, qkvwbt + (size_t)2048 * 2048, 2048, 256);
  transpose_cvt<<<dim3(64, 64, 1), 256, 0, stream>>>(outw, outwbt, 2048, 2048);
  gemm_bt<0><<<640, 256, 0, stream>>>(xb, qkvwbt, qkvb, 4096, 2560, 2048);
  rope_kernel<<<18432, 256, 0, stream>>>(qkvb, positions);
  vt_kernel<<<dim3(64, 8, 2), 256, 0, stream>>>(qkvb, vtg);
  flash_kernel<<<256, 256, 0, stream>>>(qkvb, vtg, encb);
  gemm_bt<1><<<512, 256, 0, stream>>>(encb, outwbt, d_out, 4096, 2048, 2048);
}